// Round 3
// baseline (1818.937 us; speedup 1.0000x reference)
//
#include <hip/hip_runtime.h>
#include <math.h>

// CapsuleLayer dynamic routing, MI355X fp32. Round 3: no atomics anywhere.
// B=64, In=2048, Din=16, Nc=32, Dc=32, ROUTINGS=3.
// b starts at 0 => logits_t = hat . (v0+..+v_{t-1}); never store b or hat.
// Per iter t>=1: caps_logits (A): per-(b,i) softmax max M and 1/sum invD  [1 MB]
//               caps_accum  (B): per-block (j, 16 b, 1/4 of i) recomputes hat,
//                                c = exp(hat.vsum - M)*invD, accumulates s in regs,
//                                writes 4 partials per output (plain stores).
//               reduce_squash:   sum 4 partials, squash, update VSUM / out.

#define B_TOT   64
#define IN_CAPS 2048
#define DIN     16
#define NC      32
#define DC      32
#define JD      (NC * DC)            // 1024
#define ISPLIT  4
#define I_PER   (IN_CAPS / ISPLIT)   // 512
#define STEPS   (I_PER / 32)         // 16
#define EPS_SQ  1e-7f

__device__ __forceinline__ float dot4(float4 a, float4 b) {
    return a.x * b.x + a.y * b.y + a.z * b.z + a.w * b.w;
}

// ---------------- Kernel B: fused c-weighted accumulation --------------------
// grid 512 (1D): bid = bc*128 + isp*32 + j  (so bid%8 = j%8 -> same-j same XCD)
// block 256: t = io*8 + dqi ; io in [0,32) parallel-i, dqi*4 = d-quad.
template <int UNIFORM>
__launch_bounds__(256, 2)
__global__ void caps_accum(const float* __restrict__ x,
                           const float* __restrict__ W,
                           const float* __restrict__ vsum,
                           const float* __restrict__ MD,
                           float* __restrict__ P)
{
    __shared__ float xs[16 * 640];   // 40 KB: [b][io][k] padded io-stride 20 fl

    const int t   = threadIdx.x;
    const int dqi = t & 7;
    const int io  = t >> 3;          // 0..31
    const int dq  = dqi * 4;

    const int bid = blockIdx.x;
    const int j   = bid & 31;
    const int isp = (bid >> 5) & 3;
    const int bc  = bid >> 7;
    const int b0  = bc * 16;
    const int i_origin = isp * I_PER;

    const float*  Wj = W + (size_t)j * IN_CAPS * (DC * DIN);
    const float4* xg = (const float4*)x;

    float acc[16][4];
#pragma unroll
    for (int b = 0; b < 16; ++b)
#pragma unroll
        for (int dd = 0; dd < 4; ++dd) acc[b][dd] = 0.f;

    for (int s = 0; s < STEPS; ++s) {
        const int ib = i_origin + s * 32;
        __syncthreads();
        // stage x[b0..b0+15][ib..ib+31][0..15] -> xs (padded, b128-aligned)
#pragma unroll
        for (int r = 0; r < 8; ++r) {
            const int idx  = r * 256 + t;
            const int bb   = idx >> 7;          // 0..15
            const int rest = idx & 127;         // il*4 + kq
            const int il   = rest >> 2, kq = rest & 3;
            const float4 v = xg[(size_t)(b0 + bb) * (IN_CAPS * DIN / 4)
                                + (size_t)ib * 4 + rest];
            *(float4*)&xs[bb * 640 + il * 20 + kq * 4] = v;
        }
        __syncthreads();

        const int i = ib + io;
        const float4* Wp = (const float4*)(Wj + ((size_t)i * DC + dq) * DIN);
        float4 w[16];
#pragma unroll
        for (int q = 0; q < 16; ++q) w[q] = Wp[q];

#pragma unroll
        for (int b = 0; b < 16; ++b) {
            const float4 xv0 = *(const float4*)&xs[b * 640 + io * 20 + 0];
            const float4 xv1 = *(const float4*)&xs[b * 640 + io * 20 + 4];
            const float4 xv2 = *(const float4*)&xs[b * 640 + io * 20 + 8];
            const float4 xv3 = *(const float4*)&xs[b * 640 + io * 20 + 12];
            float h[4];
#pragma unroll
            for (int dd = 0; dd < 4; ++dd) {
                h[dd] = dot4(w[dd * 4 + 0], xv0) + dot4(w[dd * 4 + 1], xv1)
                      + dot4(w[dd * 4 + 2], xv2) + dot4(w[dd * 4 + 3], xv3);
            }
            if (UNIFORM) {
#pragma unroll
                for (int dd = 0; dd < 4; ++dd) acc[b][dd] += h[dd];
            } else {
                const float4 vv =
                    *(const float4*)&vsum[((size_t)(b0 + b) * NC + j) * DC + dq];
                float lp = h[0] * vv.x + h[1] * vv.y + h[2] * vv.z + h[3] * vv.w;
                lp += __shfl_xor(lp, 1, 8);
                lp += __shfl_xor(lp, 2, 8);
                lp += __shfl_xor(lp, 4, 8);
                const float2 md =
                    *(const float2*)&MD[((size_t)(b0 + b) * IN_CAPS + i) * 2];
                const float c = __expf(lp - md.x) * md.y;
#pragma unroll
                for (int dd = 0; dd < 4; ++dd) acc[b][dd] += c * h[dd];
            }
        }
    }

    // reduce over io: lane bits 3,4,5 (io within wave) via in-wave butterflies
#pragma unroll
    for (int b = 0; b < 16; ++b)
#pragma unroll
        for (int dd = 0; dd < 4; ++dd) {
            float v = acc[b][dd];
            v += __shfl_xor(v, 8, 64);
            v += __shfl_xor(v, 16, 64);
            v += __shfl_xor(v, 32, 64);
            acc[b][dd] = v;
        }

    __syncthreads();                 // xs reuse as cross-wave scratch
    const int w_id = t >> 6, l = t & 63;
    if (l < 8) {
#pragma unroll
        for (int b = 0; b < 16; ++b)
            *(float4*)&xs[w_id * 512 + b * 32 + dq] =
                make_float4(acc[b][0], acc[b][1], acc[b][2], acc[b][3]);
    }
    __syncthreads();

    const float scale = UNIFORM ? (1.f / NC) : 1.f;
#pragma unroll
    for (int e = 0; e < 2; ++e) {
        const int idx = e * 256 + t;        // b*32 + d
        const float v = xs[idx] + xs[512 + idx] + xs[1024 + idx] + xs[1536 + idx];
        const int b = idx >> 5, d = idx & 31;
        P[((size_t)isp * B_TOT + b0 + b) * JD + j * DC + d] = v * scale;
    }
}

// ---------------- Kernel A: per-(b,i) softmax denominators -------------------
// grid (128, 4): blockIdx.x = i-chunk of 16, blockIdx.y = b-chunk of 16.
// block 256: t = j*8 + dqi.
__launch_bounds__(256, 2)
__global__ void caps_logits(const float* __restrict__ x,
                            const float* __restrict__ W,
                            const float* __restrict__ vsum,
                            float* __restrict__ MD)
{
    __shared__ float xsa[16][DIN];   // 1 KB
    __shared__ float ls[16][NC];     // 2 KB

    const int t   = threadIdx.x;
    const int j   = t >> 3;
    const int dqi = t & 7;
    const int dq  = dqi * 4;

    const int b0 = blockIdx.y * 16;
    const int i0 = blockIdx.x * 16;

    float4 vv[16];
#pragma unroll
    for (int b = 0; b < 16; ++b)
        vv[b] = *(const float4*)&vsum[((size_t)(b0 + b) * NC + j) * DC + dq];

    for (int il = 0; il < 16; ++il) {
        const int i = i0 + il;
        {
            const int bl = t >> 4, k = t & 15;
            xsa[bl][k] = x[((size_t)(b0 + bl) * IN_CAPS + i) * DIN + k];
        }
        __syncthreads();

        const float4* Wp =
            (const float4*)(W + (((size_t)j * IN_CAPS + i) * DC + dq) * DIN);
        float4 w[16];
#pragma unroll
        for (int q = 0; q < 16; ++q) w[q] = Wp[q];

#pragma unroll
        for (int b = 0; b < 16; ++b) {
            const float4 xv0 = *(const float4*)&xsa[b][0];
            const float4 xv1 = *(const float4*)&xsa[b][4];
            const float4 xv2 = *(const float4*)&xsa[b][8];
            const float4 xv3 = *(const float4*)&xsa[b][12];
            float h[4];
#pragma unroll
            for (int dd = 0; dd < 4; ++dd) {
                h[dd] = dot4(w[dd * 4 + 0], xv0) + dot4(w[dd * 4 + 1], xv1)
                      + dot4(w[dd * 4 + 2], xv2) + dot4(w[dd * 4 + 3], xv3);
            }
            float lp = h[0] * vv[b].x + h[1] * vv[b].y
                     + h[2] * vv[b].z + h[3] * vv[b].w;
            lp += __shfl_xor(lp, 1, 8);
            lp += __shfl_xor(lp, 2, 8);
            lp += __shfl_xor(lp, 4, 8);
            if (dqi == 0) ls[b][j] = lp;
        }
        __syncthreads();

        // softmax stats over j: thread -> (bb = t>>4, jj = t&15), 2 j's each
        {
            const int bb = t >> 4;
            const int jj = t & 15;
            const float l0 = ls[bb][jj];
            const float l1 = ls[bb][jj + 16];
            float m = fmaxf(l0, l1);
            m = fmaxf(m, __shfl_xor(m, 1, 16));
            m = fmaxf(m, __shfl_xor(m, 2, 16));
            m = fmaxf(m, __shfl_xor(m, 4, 16));
            m = fmaxf(m, __shfl_xor(m, 8, 16));
            float ssum = __expf(l0 - m) + __expf(l1 - m);
            ssum += __shfl_xor(ssum, 1, 16);
            ssum += __shfl_xor(ssum, 2, 16);
            ssum += __shfl_xor(ssum, 4, 16);
            ssum += __shfl_xor(ssum, 8, 16);
            if (jj == 0) {
                *(float2*)&MD[((size_t)(b0 + bb) * IN_CAPS + i) * 2] =
                    make_float2(m, 1.f / ssum);
            }
        }
        // next il: ls rewritten only after next barrier; xsa rewritten only
        // after next loop's staging (reads above already done). Need one barrier
        // before restaging xsa:  provided by loop-top __syncthreads below.
        __syncthreads();
    }
}

// Sum nparts partials (stride B_TOT*JD), squash over Dc=32 lanes, then
// mode 0: VSUM = v ; mode 1: VSUM += v ; mode 2: OUT = v
__global__ void reduce_squash(const float* __restrict__ P, int nparts,
                              float* __restrict__ VSUM,
                              float* __restrict__ OUT, int mode)
{
    const int idx = blockIdx.x * blockDim.x + threadIdx.x;  // b*1024 + jd
    float val = 0.f;
#pragma unroll 4
    for (int ig = 0; ig < nparts; ++ig)
        val += P[(size_t)ig * (B_TOT * JD) + idx];

    float s2 = val * val;
#pragma unroll
    for (int off = 16; off >= 1; off >>= 1)
        s2 += __shfl_xor(s2, off, 32);
    const float sc = s2 / (1.f + s2) * rsqrtf(s2 + EPS_SQ);
    const float v  = sc * val;
    if (mode == 0)      VSUM[idx] = v;
    else if (mode == 1) VSUM[idx] += v;
    else                OUT[idx] = v;
}

// ---------------- Fallback (round-2 atomic path, proven) ---------------------
template <int PHASE>
__launch_bounds__(256, 2)
__global__ void caps_pass_atomic(const float* __restrict__ x,
                                 const float* __restrict__ W,
                                 const float* __restrict__ vsum,
                                 float* __restrict__ S)
{
    __shared__ float xs[16][DIN];
    __shared__ float c_s[16][NC];
    __shared__ float hat_s[PHASE == 1 ? 16 * JD : 4];

    const int t    = threadIdx.x;
    const int j    = t >> 3;
    const int doff = (t & 7) * 4;
    const int jd0  = j * DC + doff;
    const int b0 = blockIdx.y * 16;
    const int i0 = blockIdx.x * 16;

    float acc[16][4];
#pragma unroll
    for (int b = 0; b < 16; ++b)
#pragma unroll
        for (int dd = 0; dd < 4; ++dd) acc[b][dd] = 0.f;

    for (int il = 0; il < 16; ++il) {
        const int i = i0 + il;
        {
            const int bl = t >> 4, k = t & 15;
            xs[bl][k] = x[((size_t)(b0 + bl) * IN_CAPS + i) * DIN + k];
        }
        __syncthreads();
        const float4* Wp =
            (const float4*)(W + (((size_t)j * IN_CAPS + i) * DC + doff) * DIN);
        float4 wreg[16];
#pragma unroll
        for (int q = 0; q < 16; ++q) wreg[q] = Wp[q];

        float lp[16];
#pragma unroll
        for (int b = 0; b < 16; ++b) {
            float h[4];
#pragma unroll
            for (int dd = 0; dd < 4; ++dd) {
                float hs = 0.f;
#pragma unroll
                for (int q4 = 0; q4 < 4; ++q4) {
                    const float4 wv = wreg[dd * 4 + q4];
                    hs += wv.x * xs[b][q4 * 4 + 0];
                    hs += wv.y * xs[b][q4 * 4 + 1];
                    hs += wv.z * xs[b][q4 * 4 + 2];
                    hs += wv.w * xs[b][q4 * 4 + 3];
                }
                h[dd] = hs;
            }
            if (PHASE == 0) {
#pragma unroll
                for (int dd = 0; dd < 4; ++dd) acc[b][dd] += h[dd];
            } else {
                *(float4*)&hat_s[b * JD + jd0] = make_float4(h[0], h[1], h[2], h[3]);
                const float4 vvl =
                    *(const float4*)&vsum[(size_t)(b0 + b) * JD + jd0];
                lp[b] = h[0] * vvl.x + h[1] * vvl.y + h[2] * vvl.z + h[3] * vvl.w;
            }
        }

        if (PHASE == 1) {
#pragma unroll
            for (int b = 0; b < 16; ++b) {
                lp[b] += __shfl_xor(lp[b], 1, 8);
                lp[b] += __shfl_xor(lp[b], 2, 8);
                lp[b] += __shfl_xor(lp[b], 4, 8);
            }
            if ((t & 7) == 0) {
#pragma unroll
                for (int b = 0; b < 16; ++b) c_s[b][j] = lp[b];
            }
            __syncthreads();
            {
                const int b  = t >> 4;
                const int jj = t & 15;
                float l0 = c_s[b][jj];
                float l1 = c_s[b][jj + 16];
                float m = fmaxf(l0, l1);
                m = fmaxf(m, __shfl_xor(m, 1, 16));
                m = fmaxf(m, __shfl_xor(m, 2, 16));
                m = fmaxf(m, __shfl_xor(m, 4, 16));
                m = fmaxf(m, __shfl_xor(m, 8, 16));
                const float e0 = __expf(l0 - m);
                const float e1 = __expf(l1 - m);
                float ssum = e0 + e1;
                ssum += __shfl_xor(ssum, 1, 16);
                ssum += __shfl_xor(ssum, 2, 16);
                ssum += __shfl_xor(ssum, 4, 16);
                ssum += __shfl_xor(ssum, 8, 16);
                const float inv = 1.f / ssum;
                c_s[b][jj]      = e0 * inv;
                c_s[b][jj + 16] = e1 * inv;
            }
            __syncthreads();
#pragma unroll
            for (int b = 0; b < 16; ++b) {
                const float c   = c_s[b][j];
                const float4 hv = *(const float4*)&hat_s[b * JD + jd0];
                acc[b][0] += c * hv.x;
                acc[b][1] += c * hv.y;
                acc[b][2] += c * hv.z;
                acc[b][3] += c * hv.w;
            }
        } else {
            __syncthreads();
        }
    }

    const float scale = (PHASE == 0) ? (1.f / NC) : 1.f;
#pragma unroll
    for (int b = 0; b < 16; ++b) {
        float* dst = &S[(size_t)(b0 + b) * JD + jd0];
#pragma unroll
        for (int dd = 0; dd < 4; ++dd)
            atomicAdd(dst + dd, acc[b][dd] * scale);
    }
}

extern "C" void kernel_launch(void* const* d_in, const int* in_sizes, int n_in,
                              void* d_out, int out_size, void* d_ws, size_t ws_size,
                              hipStream_t stream)
{
    const float* x = (const float*)d_in[0];   // [64, 2048, 16]
    const float* W = (const float*)d_in[1];   // [32, 2048, 32, 16]
    float* out = (float*)d_out;               // [64, 32, 32]

    const size_t P_elems  = (size_t)ISPLIT * B_TOT * JD;   // 256K floats
    const size_t V_elems  = (size_t)B_TOT * JD;            // 64K floats
    const size_t MD_elems = (size_t)B_TOT * IN_CAPS * 2;   // 256K floats
    const size_t need = (P_elems + V_elems + MD_elems) * sizeof(float); // ~2.25 MB

    if (ws_size >= need) {
        float* P    = (float*)d_ws;
        float* VSUM = P + P_elems;
        float* MD   = VSUM + V_elems;

        caps_accum<1><<<512, 256, 0, stream>>>(x, W, nullptr, nullptr, P);
        reduce_squash<<<B_TOT * JD / 256, 256, 0, stream>>>(P, ISPLIT, VSUM, out, 0);

        caps_logits<<<dim3(128, 4), 256, 0, stream>>>(x, W, VSUM, MD);
        caps_accum<0><<<512, 256, 0, stream>>>(x, W, VSUM, MD, P);
        reduce_squash<<<B_TOT * JD / 256, 256, 0, stream>>>(P, ISPLIT, VSUM, out, 1);

        caps_logits<<<dim3(128, 4), 256, 0, stream>>>(x, W, VSUM, MD);
        caps_accum<0><<<512, 256, 0, stream>>>(x, W, VSUM, MD, P);
        reduce_squash<<<B_TOT * JD / 256, 256, 0, stream>>>(P, ISPLIT, VSUM, out, 2);
    } else {
        // atomic fallback (round-2 behavior)
        float* S    = (float*)d_ws;
        float* VSUM = S + V_elems;
        const dim3 grid(128, 4), blk(256);
        const size_t sbytes = V_elems * sizeof(float);
        hipMemsetAsync(S, 0, sbytes, stream);
        caps_pass_atomic<0><<<grid, blk, 0, stream>>>(x, W, nullptr, S);
        reduce_squash<<<B_TOT * JD / 256, 256, 0, stream>>>(S, 1, VSUM, out, 0);
        hipMemsetAsync(S, 0, sbytes, stream);
        caps_pass_atomic<1><<<grid, blk, 0, stream>>>(x, W, VSUM, S);
        reduce_squash<<<B_TOT * JD / 256, 256, 0, stream>>>(S, 1, VSUM, out, 1);
        hipMemsetAsync(S, 0, sbytes, stream);
        caps_pass_atomic<1><<<grid, blk, 0, stream>>>(x, W, VSUM, S);
        reduce_squash<<<B_TOT * JD / 256, 256, 0, stream>>>(S, 1, VSUM, out, 2);
    }
}

// Round 4
// 902.161 us; speedup vs baseline: 2.0162x; 2.0162x over previous
//
#include <hip/hip_runtime.h>
#include <math.h>

// CapsuleLayer dynamic routing, MI355X fp32. Round 4.
// B=64, In=2048, Din=16, Nc=32, Dc=32, ROUTINGS=3.
// b starts at 0 => logits_t = hat . (v0+..+v_{t-1}); never store b or hat.
// One fused kernel per routing iteration (hat computed ONCE per pass, in regs):
//   stage x -> hat h[8][4] per thread -> (logits -> softmax in-block) ->
//   c-weighted accumulate in regs -> atomicAdd into n_slots partial buffers.
// n_slots chosen from ws_size at launch (pow2, 16-way contention at n=8).
// reduce_squash: sum slots, squash, update VSUM/out, re-zero P for next pass.

#define B_TOT   64
#define IN_CAPS 2048
#define DIN     16
#define NC      32
#define DC      32
#define JD      (NC * DC)                  // 1024
#define B_CHUNK 8
#define I_CHUNK 16
#define N_IG    (IN_CAPS / I_CHUNK)        // 128
#define EPS_SQ  1e-7f
#define SLOT_ELEMS ((size_t)B_TOT * JD)    // 65536 floats = 256 KB

__device__ __forceinline__ float dot4(float4 a, float4 b) {
    return a.x * b.x + a.y * b.y + a.z * b.z + a.w * b.w;
}

// grid (128 ig, 8 bg), block 256: t = j*8 + dqi.
// Blocks sharing ig have bid stride 128 (=0 mod 8) -> same XCD -> shared W-slice
// in that XCD's L2; slot = ig & mask -> partial buffer also XCD-local.
template <int PHASE>
__launch_bounds__(256, 2)
__global__ void caps_fused(const float* __restrict__ x,
                           const float* __restrict__ W,
                           const float* __restrict__ vsum,
                           float* __restrict__ P,
                           int slot_mask, int store_mode)
{
    __shared__ float xs[B_CHUNK][DIN];   // 512 B
    __shared__ float ls[B_CHUNK][NC];    // 1 KB: logits, then c

    const int t  = threadIdx.x;
    const int j  = t >> 3;               // 0..31
    const int dq = (t & 7) * 4;          // 0,4,..,28
    const int ig = blockIdx.x;           // 0..127
    const int b0 = blockIdx.y * B_CHUNK;
    const int i0 = ig * I_CHUNK;

    float acc[B_CHUNK][4];
#pragma unroll
    for (int b = 0; b < B_CHUNK; ++b)
#pragma unroll
        for (int dd = 0; dd < 4; ++dd) acc[b][dd] = 0.f;

    for (int il = 0; il < I_CHUNK; ++il) {
        const int i = i0 + il;

        __syncthreads();                 // xs/ls safe to rewrite
        if (t < B_CHUNK * DIN) {
            const int bl = t >> 4, k = t & 15;
            xs[bl][k] = x[((size_t)(b0 + bl) * IN_CAPS + i) * DIN + k];
        }
        __syncthreads();

        // this thread's W slice: (j, dq..dq+3, all 16 k) = 64 contig floats
        const float4* Wp =
            (const float4*)(W + (((size_t)j * IN_CAPS + i) * DC + dq) * DIN);
        float4 w[16];
#pragma unroll
        for (int q = 0; q < 16; ++q) w[q] = Wp[q];

        float h[B_CHUNK][4];             // hat values, live across barriers
#pragma unroll
        for (int b = 0; b < B_CHUNK; ++b) {
            const float4 x0 = *(const float4*)&xs[b][0];
            const float4 x1 = *(const float4*)&xs[b][4];
            const float4 x2 = *(const float4*)&xs[b][8];
            const float4 x3 = *(const float4*)&xs[b][12];
#pragma unroll
            for (int dd = 0; dd < 4; ++dd) {
                h[b][dd] = dot4(w[dd * 4 + 0], x0) + dot4(w[dd * 4 + 1], x1)
                         + dot4(w[dd * 4 + 2], x2) + dot4(w[dd * 4 + 3], x3);
            }
        }

        if (PHASE == 0) {
#pragma unroll
            for (int b = 0; b < B_CHUNK; ++b)
#pragma unroll
                for (int dd = 0; dd < 4; ++dd) acc[b][dd] += h[b][dd];
        } else {
            // logits: lp = h . vsum, reduced over the 8 d-quad threads
#pragma unroll
            for (int b = 0; b < B_CHUNK; ++b) {
                const float4 vv =
                    *(const float4*)&vsum[((size_t)(b0 + b) * NC + j) * DC + dq];
                float lp = h[b][0] * vv.x + h[b][1] * vv.y
                         + h[b][2] * vv.z + h[b][3] * vv.w;
                lp += __shfl_xor(lp, 1, 8);
                lp += __shfl_xor(lp, 2, 8);
                lp += __shfl_xor(lp, 4, 8);
                if ((t & 7) == 0) ls[b][j] = lp;
            }
            __syncthreads();

            // softmax over j: 256 threads = 8 b x 32 j, one (b,j) per thread
            {
                const int bb = t >> 5;       // 0..7
                const int jj = t & 31;       // 0..31
                const float l = ls[bb][jj];
                float m = l;
                m = fmaxf(m, __shfl_xor(m, 1, 32));
                m = fmaxf(m, __shfl_xor(m, 2, 32));
                m = fmaxf(m, __shfl_xor(m, 4, 32));
                m = fmaxf(m, __shfl_xor(m, 8, 32));
                m = fmaxf(m, __shfl_xor(m, 16, 32));
                const float e = __expf(l - m);
                float ssum = e;
                ssum += __shfl_xor(ssum, 1, 32);
                ssum += __shfl_xor(ssum, 2, 32);
                ssum += __shfl_xor(ssum, 4, 32);
                ssum += __shfl_xor(ssum, 8, 32);
                ssum += __shfl_xor(ssum, 16, 32);
                ls[bb][jj] = e / ssum;       // own (b,j) slot: no race
            }
            __syncthreads();

            // c-weighted accumulate (h still in registers)
#pragma unroll
            for (int b = 0; b < B_CHUNK; ++b) {
                const float c = ls[b][j];
                acc[b][0] += c * h[b][0];
                acc[b][1] += c * h[b][1];
                acc[b][2] += c * h[b][2];
                acc[b][3] += c * h[b][3];
            }
        }
    }

    const float scale = (PHASE == 0) ? (1.f / NC) : 1.f;
    if (store_mode) {
        // n_slots == 128: each ig owns its slot, plain coalesced stores
        float* dst = P + (size_t)ig * SLOT_ELEMS + (size_t)b0 * JD + j * DC + dq;
#pragma unroll
        for (int b = 0; b < B_CHUNK; ++b)
            *(float4*)(dst + (size_t)b * JD) =
                make_float4(acc[b][0] * scale, acc[b][1] * scale,
                            acc[b][2] * scale, acc[b][3] * scale);
    } else {
        const int slot = ig & slot_mask;
        float* dst = P + (size_t)slot * SLOT_ELEMS + (size_t)b0 * JD + j * DC + dq;
#pragma unroll
        for (int b = 0; b < B_CHUNK; ++b)
#pragma unroll
            for (int dd = 0; dd < 4; ++dd)
                atomicAdd(dst + (size_t)b * JD + dd, acc[b][dd] * scale);
    }
}

// Sum nparts slots, squash over Dc=32 (32 consecutive lanes = one capsule),
// mode 0: VSUM = v ; 1: VSUM += v ; 2: OUT = v.  zero_after: re-zero P slots.
__global__ void reduce_squash(float* __restrict__ P, int nparts,
                              float* __restrict__ VSUM,
                              float* __restrict__ OUT, int mode, int zero_after)
{
    const int idx = blockIdx.x * blockDim.x + threadIdx.x;  // b*1024 + jd
    float val = 0.f;
    for (int s = 0; s < nparts; ++s)
        val += P[(size_t)s * SLOT_ELEMS + idx];
    if (zero_after) {
        for (int s = 0; s < nparts; ++s)
            P[(size_t)s * SLOT_ELEMS + idx] = 0.f;
    }

    float s2 = val * val;
#pragma unroll
    for (int off = 16; off >= 1; off >>= 1)
        s2 += __shfl_xor(s2, off, 32);
    const float sc = s2 / (1.f + s2) * rsqrtf(s2 + EPS_SQ);
    const float v  = sc * val;
    if (mode == 0)      VSUM[idx] = v;
    else if (mode == 1) VSUM[idx] += v;
    else                OUT[idx] = v;
}

extern "C" void kernel_launch(void* const* d_in, const int* in_sizes, int n_in,
                              void* d_out, int out_size, void* d_ws, size_t ws_size,
                              hipStream_t stream)
{
    const float* x = (const float*)d_in[0];   // [64, 2048, 16]
    const float* W = (const float*)d_in[1];   // [32, 2048, 32, 16]
    float* out = (float*)d_out;               // [64, 32, 32]

    // choose n_slots (pow2) from workspace: P = n_slots*256KB, then VSUM 256KB
    const size_t ws_floats = ws_size / sizeof(float);
    size_t avail = (ws_floats > SLOT_ELEMS) ? ws_floats - SLOT_ELEMS : 0;
    int n_slots = 1;
    while (n_slots < N_IG && (size_t)(n_slots * 2) * SLOT_ELEMS <= avail)
        n_slots *= 2;
    const int store_mode = (n_slots == N_IG) ? 1 : 0;
    const int slot_mask  = n_slots - 1;

    float* P    = (float*)d_ws;
    float* VSUM = P + (size_t)n_slots * SLOT_ELEMS;

    const dim3 grid(N_IG, B_TOT / B_CHUNK);   // 128 x 8 = 1024 blocks
    const dim3 blk(256);
    const int  rs_grid = (B_TOT * JD) / 256;  // 256

    if (!store_mode)
        hipMemsetAsync(P, 0, (size_t)n_slots * SLOT_ELEMS * sizeof(float), stream);

    // iter 0: uniform c = 1/32
    caps_fused<0><<<grid, blk, 0, stream>>>(x, W, nullptr, P, slot_mask, store_mode);
    reduce_squash<<<rs_grid, 256, 0, stream>>>(P, n_slots, VSUM, out, 0, !store_mode);

    // iter 1: logits = hat . v0
    caps_fused<1><<<grid, blk, 0, stream>>>(x, W, VSUM, P, slot_mask, store_mode);
    reduce_squash<<<rs_grid, 256, 0, stream>>>(P, n_slots, VSUM, out, 1, !store_mode);

    // iter 2: logits = hat . (v0+v1)
    caps_fused<1><<<grid, blk, 0, stream>>>(x, W, VSUM, P, slot_mask, store_mode);
    reduce_squash<<<rs_grid, 256, 0, stream>>>(P, n_slots, VSUM, out, 2, 0);
}